// Round 7
// baseline (132.896 us; speedup 1.0000x reference)
//
#include <hip/hip_runtime.h>

// SSM DPLR kernel: K[h,l] = 2*Re(C_h . dA_h^l . dB_h), dA = diag(g) + q r^T.
// R6: l = 64i+j as before, but the C-chain advances TWO indices per barrier:
//   C_{i+2} = C_i * M2,  M2 = dA^128 (closed divided-difference form, T128),
//   waves 0-3 = even chain, waves 4-7 = odd chain (seed C1 = C*M via T64).
//   15 chain barriers instead of 31.

#define LL 2048

struct C2 { float re, im; };

__device__ __forceinline__ C2 cmul(C2 a, C2 b){ return {a.re*b.re - a.im*b.im, a.re*b.im + a.im*b.re}; }
__device__ __forceinline__ C2 cadd(C2 a, C2 b){ return {a.re+b.re, a.im+b.im}; }
__device__ __forceinline__ C2 csub(C2 a, C2 b){ return {a.re-b.re, a.im-b.im}; }
__device__ __forceinline__ C2 cinv(C2 a){ float s=1.0f/(a.re*a.re+a.im*a.im); return {a.re*s, -a.im*s}; }
__device__ __forceinline__ C2 cscale(float s, C2 a){ return {s*a.re, s*a.im}; }
__device__ __forceinline__ C2 ld2(float2 v){ return {v.x, v.y}; }
__device__ __forceinline__ float2 st2(C2 v){ return make_float2(v.re, v.im); }

template<int CTRL>
__device__ __forceinline__ float dpp_add(float x){
  int t = __builtin_amdgcn_update_dpp(0, __float_as_int(x), CTRL, 0xF, 0xF, true);
  return x + __int_as_float(t);
}
__device__ __forceinline__ float wave_sum63(float x){
  x = dpp_add<0xB1>(x);   // quad_perm xor1
  x = dpp_add<0x4E>(x);   // quad_perm xor2
  x = dpp_add<0x124>(x);  // row_ror:4
  x = dpp_add<0x128>(x);  // row_ror:8
  x = dpp_add<0x142>(x);  // row_bcast:15
  x = dpp_add<0x143>(x);  // row_bcast:31
  return x;
}
__device__ __forceinline__ float bcast63(float x){
  return __int_as_float(__builtin_amdgcn_readlane(__float_as_int(x), 63));
}
__device__ __forceinline__ float rdl(float v, int l){
  return __int_as_float(__builtin_amdgcn_readlane(__float_as_int(v), l));
}
__device__ __forceinline__ C2 rdl2(C2 v, int l){
  return { rdl(v.re, l), rdl(v.im, l) };
}
// lane i <- lane i-1, lane0 <- 0   (wave_shr:1)
__device__ __forceinline__ float shr1(float x){
  return __int_as_float(__builtin_amdgcn_update_dpp(0, __float_as_int(x), 0x138, 0xF, 0xF, true));
}

__global__ __launch_bounds__(512) void ssm_dplr_kernel(
    const float* __restrict__ A_real, const float* __restrict__ A_imag,
    const float* __restrict__ B_real, const float* __restrict__ B_imag,
    const float* __restrict__ P_real, const float* __restrict__ P_imag,
    const float* __restrict__ C_real, const float* __restrict__ C_imag,
    const float* __restrict__ log_dt, float* __restrict__ out)
{
    const int h    = blockIdx.x;
    const int t    = threadIdx.x;
    const int lane = t & 63;
    const int widu = __builtin_amdgcn_readfirstlane(t >> 6);   // SGPR wave id 0..7

    extern __shared__ char sm[];
    float2* Xbuf   = (float2*)sm;              // 64x64: G powers, then X  [32 KB]
    float2* Cs     = (float2*)(sm + 32768);    // 32x64 C_i rows           [16 KB]
    float2* prt    = (float2*)(sm + 49152);    // 3 x 512                  [12 KB]
    float2* Tg64A  = (float2*)(sm + 61440);    // 64 each:
    float2* Tp64A  = Tg64A + 64;
    float2* Tg128A = Tg64A + 128;
    float2* Tp128A = Tg64A + 192;

    // ---------------- setup (every wave, per-lane n = lane) ----------------
    const int idx = h * 64 + lane;
    const float dt = expf(log_dt[h]);
    const float c  = 0.5f * dt;

    const C2 lam = { -A_real[idx], -A_imag[idx] };
    const C2 p   = {  P_real[idx],  P_imag[idx] };
    const C2 Bv  = {  B_real[idx],  B_imag[idx] };
    const C2 Cv  = {  C_real[idx],  C_imag[idx] };
    const C2 pc  = { p.re, -p.im };

    const C2 d = cinv(C2{ 1.0f - c*lam.re, -c*lam.im });
    const C2 g = cmul(d, C2{ 1.0f + c*lam.re, c*lam.im });   // diag of dA

    C2 sv = cscale(p.re*p.re + p.im*p.im, d);
    C2 uv = cmul(cmul(d, pc), Bv);
    sv.re = bcast63(wave_sum63(sv.re)); sv.im = bcast63(wave_sum63(sv.im));
    uv.re = bcast63(wave_sum63(uv.re)); uv.im = bcast63(wave_sum63(uv.im));

    const C2 beta  = cscale(c, cinv(C2{ 1.0f + c*sv.re, c*sv.im }));
    const C2 bs    = cmul(beta, sv);
    const C2 gamma = { -c*(1.0f - bs.re), c*bs.im };

    const C2 q  = cmul(d, p);
    const C2 r  = cmul(pc, csub(gamma, cmul(beta, g)));
    const C2 x0 = cscale(dt, csub(cmul(d, Bv), cmul(cmul(beta, uv), q)));  // dB
    const C2 rq  = cmul(r, q);
    const C2 rx  = cmul(r, x0);

    const C2 g2   = cmul(g,  g);
    const C2 g4   = cmul(g2, g2);
    const C2 g8   = cmul(g4, g4);
    const C2 g16  = cmul(g8, g8);
    const C2 g32  = cmul(g16,g16);
    const C2 g64  = cmul(g32,g32);
    const C2 g128 = cmul(g64,g64);
    const C2 rqg  = cmul(rq, g64);      // coeffs for w_{64+b}

    // ---------------- G-gen: G[j][n] = g_n^j, rows j in [8w, 8w+8) ----------------
    {
        C2 cur = {1.0f, 0.0f};
        if (widu & 1) cur = g8;
        if (widu & 2) cur = cmul(cur, g16);
        if (widu & 4) cur = cmul(cur, g32);
        #pragma unroll
        for (int jj = 0; jj < 8; ++jj) {
            const int j = 8*widu + jj;
            Xbuf[j*64 + ((lane + j) & 63)] = st2(cur);   // rotated columns
            cur = cmul(cur, g);
        }
    }
    __syncthreads();   // B1

    // ---------------- partials: w_j (rq), w_{64+j} (rq*g64), a_j (rx) ----------------
    {
        C2 accw = {0,0}, accv = {0,0}, acca = {0,0};
        #pragma unroll
        for (int kk = 0; kk < 8; ++kk) {
            const int n = 8*widu + kk;
            const C2 Gv = ld2(Xbuf[lane*64 + ((n + lane) & 63)]);
            const C2 fw = rdl2(rq,  n);
            const C2 fv = rdl2(rqg, n);
            const C2 fa = rdl2(rx,  n);
            accw = cadd(accw, cmul(Gv, fw));
            accv = cadd(accv, cmul(Gv, fv));
            acca = cadd(acca, cmul(Gv, fa));
        }
        prt[widu*64 + lane]        = st2(accw);
        prt[512 + widu*64 + lane]  = st2(accv);
        prt[1024 + widu*64 + lane] = st2(acca);
    }
    __syncthreads();   // B2

    // ---------------- solo region ----------------
    if (widu == 0) {
        // reduce w (0..63) and a
        C2 wl = {0,0}, va = {0,0};
        #pragma unroll
        for (int w2 = 0; w2 < 8; ++w2) {
            const float2 wv = prt[w2*64 + lane];
            const float2 av = prt[1024 + w2*64 + lane];
            wl.re += wv.x; wl.im += wv.y;
            va.re += av.x; va.im += av.y;
        }
        // sigma solve: sigma_j = a_j + sum_{i<j} w_{j-1-i} sigma_i
        C2 so = {0,0};
        C2 wsh = { shr1(wl.re), shr1(wl.im) };
        for (int j = 0; j < 64; ++j) {
            const float sr = rdl(va.re, j);
            const float si = rdl(va.im, j);
            if (lane == j) { so.re = sr; so.im = si; }
            va.re += wsh.re*sr - wsh.im*si;
            va.im += wsh.re*si + wsh.im*sr;
            wsh.re = shr1(wsh.re);
            wsh.im = shr1(wsh.im);
        }
        // X rebuild: X_{j+1} = g.*X_j + sigma_j q  (overwrites G table)
        C2 x = x0;
        for (int j = 0; j < 64; ++j) {
            Xbuf[j*64 + ((lane + j) & 63)] = st2(x);
            const float sjr = rdl(so.re, j);
            const float sji = rdl(so.im, j);
            const float nr = g.re*x.re - g.im*x.im + sjr*q.re - sji*q.im;
            const float ni = g.re*x.im + g.im*x.re + sjr*q.im + sji*q.re;
            x.re = nr; x.im = ni;
        }
    } else if (widu == 1) {
        // reduce w halves
        C2 wl0 = {0,0}, wl1 = {0,0};
        #pragma unroll
        for (int w2 = 0; w2 < 8; ++w2) {
            const float2 a0 = prt[w2*64 + lane];
            const float2 a1 = prt[512 + w2*64 + lane];
            wl0.re += a0.x; wl0.im += a0.y;
            wl1.re += a1.x; wl1.im += a1.y;
        }
        // tau solve over 128 coeffs (2 per lane): t_j = w_j + sum_{i<j} w_{j-1-i} t_i
        C2 t0 = {0,0}, t1 = {0,0};
        C2 v0 = wl0, v1 = wl1;
        C2 wsh0 = { shr1(wl0.re), shr1(wl0.im) };
        C2 wsh1;
        {
            const float c63r = rdl(wl0.re, 63);
            const float c63i = rdl(wl0.im, 63);
            wsh1.re = shr1(wl1.re); wsh1.im = shr1(wl1.im);
            if (lane == 0) { wsh1.re = c63r; wsh1.im = c63i; }
        }
        for (int j = 0; j < 64; ++j) {
            const float sr = rdl(v0.re, j);
            const float si = rdl(v0.im, j);
            if (lane == j) { t0.re = sr; t0.im = si; }
            v0.re += wsh0.re*sr - wsh0.im*si;
            v0.im += wsh0.re*si + wsh0.im*sr;
            v1.re += wsh1.re*sr - wsh1.im*si;
            v1.im += wsh1.re*si + wsh1.im*sr;
            const float cr = rdl(wsh0.re, 63);
            const float ci = rdl(wsh0.im, 63);
            wsh0.re = shr1(wsh0.re); wsh0.im = shr1(wsh0.im);
            wsh1.re = shr1(wsh1.re); wsh1.im = shr1(wsh1.im);
            if (lane == 0) { wsh1.re = cr; wsh1.im = ci; }
        }
        for (int j = 0; j < 64; ++j) {
            const float sr = rdl(v1.re, j);
            const float si = rdl(v1.im, j);
            if (lane == j) { t1.re = sr; t1.im = si; }
            v1.re += wsh1.re*sr - wsh1.im*si;
            v1.im += wsh1.re*si + wsh1.im*sr;
            wsh1.re = shr1(wsh1.re); wsh1.im = shr1(wsh1.im);
        }
        // T64(z) = z*P(z), P from t_0..t_62 ; T64' = P + z P'
        {
            C2 pp = rdl2(t0, 0);
            C2 dd = {0,0};
            for (int i = 1; i <= 62; ++i) {
                const C2 ti = rdl2(t0, i);
                const C2 nd = cadd(cmul(dd, g), pp);
                pp = cadd(cmul(pp, g), ti);
                dd = nd;
            }
            Tg64A[lane] = st2(cmul(g, pp));
            Tp64A[lane] = st2(cadd(pp, cmul(g, dd)));
        }
        // T128 from t_0..t_126
        {
            C2 pp = rdl2(t0, 0);
            C2 dd = {0,0};
            for (int i = 1; i <= 63; ++i) {
                const C2 ti = rdl2(t0, i);
                const C2 nd = cadd(cmul(dd, g), pp);
                pp = cadd(cmul(pp, g), ti);
                dd = nd;
            }
            for (int i = 64; i <= 126; ++i) {
                const C2 ti = rdl2(t1, i - 64);
                const C2 nd = cadd(cmul(dd, g), pp);
                pp = cadd(cmul(pp, g), ti);
                dd = nd;
            }
            Tg128A[lane] = st2(cmul(g, pp));
            Tp128A[lane] = st2(cadd(pp, cmul(g, dd)));
        }
    }
    __syncthreads();   // B3

    // ---------------- M2 build (all waves): rows n = 16*(widu&3)+k, cols m=lane ----------------
    C2 M2k[16];
    {
        const C2 Tgm = ld2(Tg128A[lane]);
        #pragma unroll
        for (int k = 0; k < 16; ++k) {
            const int n = 16*(widu & 3) + k;
            const C2 gn    = rdl2(g,    n);
            const C2 qn    = rdl2(q,    n);
            const C2 g128n = rdl2(g128, n);
            const C2 Tgn   = rdl2(Tgm,  n);
            const C2 idm   = cinv(csub(gn, g));   // inf on n==lane, overwritten
            const C2 num   = cmul(r, cadd(csub(g128n, g128), csub(Tgn, Tgm)));
            M2k[k] = cmul(cmul(qn, num), idm);
        }
        if ((lane >> 4) == (widu & 3)) {
            const int k0 = lane & 15;
            const C2 Tp   = ld2(Tp128A[lane]);
            const C2 g127 = cmul(g128, cinv(g));
            const C2 S    = cmul(r, cadd(cscale(128.0f, g127), Tp));
            M2k[k0] = cadd(g128, cmul(q, S));
        }
    }

    // ---------------- seed: waves 4-7 compute C1 = C0 * M (via T64) ----------------
    if (widu >= 4) {
        C2 Mk64[16];
        const C2 Tgm = ld2(Tg64A[lane]);
        #pragma unroll
        for (int k = 0; k < 16; ++k) {
            const int n = 16*(widu - 4) + k;
            const C2 gn   = rdl2(g,   n);
            const C2 qn   = rdl2(q,   n);
            const C2 g64n = rdl2(g64, n);
            const C2 Tgn  = rdl2(Tgm, n);
            const C2 idm  = cinv(csub(gn, g));
            const C2 num  = cmul(r, cadd(csub(g64n, g64), csub(Tgn, Tgm)));
            Mk64[k] = cmul(cmul(qn, num), idm);
        }
        if ((lane >> 4) == (widu - 4)) {
            const int k0 = lane & 15;
            const C2 Tp  = ld2(Tp64A[lane]);
            const C2 g63 = cmul(g64, cinv(g));
            const C2 S   = cmul(r, cadd(cscale(64.0f, g63), Tp));
            Mk64[k0] = cadd(g64, cmul(q, S));
        }
        C2 acc = {0,0};
        #pragma unroll
        for (int k = 0; k < 16; ++k) {
            const int n = 16*(widu - 4) + k;
            const float cr  = rdl(Cv.re, n);
            const float cim = rdl(Cv.im, n);
            acc.re += cr*Mk64[k].re - cim*Mk64[k].im;
            acc.im += cr*Mk64[k].im + cim*Mk64[k].re;
        }
        prt[512 + widu*64 + lane] = st2(acc);   // bufB slots 4..7
    }
    __syncthreads();   // B4

    // chain state: waves 0-3 hold C_{2a}, waves 4-7 hold C_{2a+1}
    C2 Cc;
    if (widu < 4) {
        Cc = Cv;                                // C_0
    } else {
        const float2 p4 = prt[512 + 256 + lane], p5 = prt[512 + 320 + lane];
        const float2 p6 = prt[512 + 384 + lane], p7 = prt[512 + 448 + lane];
        Cc.re = (p4.x + p5.x) + (p6.x + p7.x);
        Cc.im = (p4.y + p5.y) + (p6.y + p7.y);  // C_1
    }

    // ---------------- dual chain: 15 barrier-iterations ----------------
    for (int a = 0; a < 16; ++a) {
        if (widu == 0) Cs[(2*a)*64 + lane]   = st2(Cc);
        if (widu == 4) Cs[(2*a+1)*64 + lane] = st2(Cc);
        if (a == 15) break;
        C2 acc = {0,0};
        #pragma unroll
        for (int k = 0; k < 16; ++k) {
            const int n = 16*(widu & 3) + k;
            const float cr  = rdl(Cc.re, n);
            const float cim = rdl(Cc.im, n);
            acc.re += cr*M2k[k].re - cim*M2k[k].im;
            acc.im += cr*M2k[k].im + cim*M2k[k].re;
        }
        float2* buf = prt + (a & 1)*512;
        buf[widu*64 + lane] = st2(acc);
        __syncthreads();
        const int base = (widu < 4) ? 0 : 256;
        const float2 p0 = buf[base + lane],       p1 = buf[base + 64 + lane];
        const float2 p2 = buf[base + 128 + lane], p3 = buf[base + 192 + lane];
        Cc.re = (p0.x + p1.x) + (p2.x + p3.x);
        Cc.im = (p0.y + p1.y) + (p2.y + p3.y);
    }
    __syncthreads();   // B5

    // ---------------- output: K[64i+j] = 2 Re( sum_n C_i[n] X_j[n] ), i in [4w,4w+4) ----------------
    {
        const int j = lane;
        C2 Csr[4];
        #pragma unroll
        for (int rr = 0; rr < 4; ++rr) Csr[rr] = ld2(Cs[(4*widu + rr)*64 + lane]);
        float accK[4] = {0,0,0,0};
        #pragma unroll 8
        for (int n = 0; n < 64; ++n) {
            const float2 xv = Xbuf[j*64 + ((n + j) & 63)];
            #pragma unroll
            for (int rr = 0; rr < 4; ++rr) {
                accK[rr] += rdl(Csr[rr].re, n)*xv.x - rdl(Csr[rr].im, n)*xv.y;
            }
        }
        float* outh = out + h * LL;
        #pragma unroll
        for (int rr = 0; rr < 4; ++rr) {
            outh[(4*widu + rr)*64 + j] = 2.0f * accK[rr];
        }
    }
}

extern "C" void kernel_launch(void* const* d_in, const int* in_sizes, int n_in,
                              void* d_out, int out_size, void* d_ws, size_t ws_size,
                              hipStream_t stream) {
    const float* A_real = (const float*)d_in[0];
    const float* A_imag = (const float*)d_in[1];
    const float* B_real = (const float*)d_in[2];
    const float* B_imag = (const float*)d_in[3];
    const float* P_real = (const float*)d_in[4];
    const float* P_imag = (const float*)d_in[5];
    const float* C_real = (const float*)d_in[6];
    const float* C_imag = (const float*)d_in[7];
    const float* log_dt = (const float*)d_in[8];
    float* out = (float*)d_out;

    const size_t lds = 61440 + 256*sizeof(float2);   // 63488 B
    ssm_dplr_kernel<<<256, 512, lds, stream>>>(
        A_real, A_imag, B_real, B_imag, P_real, P_imag,
        C_real, C_imag, log_dt, out);
}